// Round 12
// baseline (97.508 us; speedup 1.0000x reference)
//
#include <hip/hip_runtime.h>

#define S 2000
#define P 2500
#define R 5
#define HALF (S / 2)      // 1000 float4 elements per row
#define NIT 16            // ceil(HALF/64)

typedef float floatx4 __attribute__((ext_vector_type(4)));

// R10 structure exactly (4 waves/WG, one (h,r,p) job per wave, filtration in
// LDS, zero global loads in hot loop) + ONE change: gm stores are
// nontemporal (evict-first) to avoid L2 write-allocate churn on the 400MB
// once-written stream.
__global__ __launch_bounds__(256) void grad_kernel(
    const float* __restrict__ filtration,   // (S,2) interleaved
    const float* __restrict__ bars0,        // (P,R)
    const float* __restrict__ bars1,        // (P,R)
    const float* __restrict__ sample_pts,   // (P,2)
    float* __restrict__ out,                // (2,P,R)
    float* __restrict__ gm0, float* __restrict__ gc0,
    float* __restrict__ gm1, float* __restrict__ gc1)
{
    __shared__ floatx4 sf[HALF];           // 16 KB

    int tid = threadIdx.x;
    const floatx4* filt4 = (const floatx4*)filtration;
#pragma unroll
    for (int i = 0; i < NIT / 4; ++i) {
        int idx = tid + 256 * i;
        if (idx < HALF) sf[idx] = filt4[idx];
    }

    int job = blockIdx.x * 4 + (tid >> 6);   // h*(R*P) + r*P + p
    int lane = tid & 63;
    int h = job / (R * P);
    int rem = job - h * (R * P);
    int r = rem / P;
    int p = rem - r * P;

    const float* bars = h ? bars1 : bars0;
    float* gm = h ? gm1 : gm0;
    float* gc = h ? gc1 : gc0;

    float bar = bars[p * R + r];
    float scale = bar + 0.01f;               // GRID_RES
    float ptx = sample_pts[2 * p];
    float pty = sample_pts[2 * p + 1];
    float psum = ptx + pty;

    float lxk[5], lyk[5];
#pragma unroll
    for (int k = 0; k < 5; ++k) {
        float ks = (float)(k - 2) * scale;   // exact mul, k-2 in {-2..2}
        lxk[k] = ks + ptx;                   // single rounding (matches np)
        lyk[k] = ks + pty;
    }
    float lastx = lxk[4];
    float lasty = lyk[4];

    if (lane == 0) out[(size_t)h * (P * R) + p * R + r] = bar;

    float* gmrow = gm + ((size_t)rem) * (size_t)(2 * S);

    bool aUx = false, aLx = false, aUy = false, aLy = false;

    __syncthreads();                         // staging done (only barrier)

#pragma unroll
    for (int it = 0; it < NIT; ++it) {
        int j = lane + 64 * it;
        if (it < NIT - 1 || j < HALF) {      // compile-time for it<15
            floatx4 f = sf[j];               // ds_read_b128 (lgkmcnt)
            floatx4 o;
            {   // pair 0 (s = 2j)
                float fx = f.x, fy = f.y;
                float tolx = __fadd_rn(0.01f, __fmul_rn(1e-5f, __builtin_fabsf(fx)));
                float toly = __fadd_rn(0.01f, __fmul_rn(1e-5f, __builtin_fabsf(fy)));
                float mx = fminf(fminf(fminf(__builtin_fabsf(lxk[0] - fx),
                                             __builtin_fabsf(lxk[1] - fx)),
                                       fminf(__builtin_fabsf(lxk[2] - fx),
                                             __builtin_fabsf(lxk[3] - fx))),
                                 __builtin_fabsf(lxk[4] - fx));
                float my = fminf(fminf(fminf(__builtin_fabsf(lyk[0] - fy),
                                             __builtin_fabsf(lyk[1] - fy)),
                                       fminf(__builtin_fabsf(lyk[2] - fy),
                                             __builtin_fabsf(lyk[3] - fy))),
                                 __builtin_fabsf(lyk[4] - fy));
                bool cx = (mx <= tolx) && (fy <= lasty);
                bool cy = (my <= toly) && (fx <= lastx);
                float fsum = fx + fy;
                bool ab = fsum > psum, be = fsum < psum;
                float sgn = ab ? 1.0f : (be ? -1.0f : 0.0f);
                o.x = cx ? sgn : 0.0f;
                o.y = cy ? sgn : 0.0f;
                aUx = aUx || (cx && ab);  aLx = aLx || (cx && be);
                aUy = aUy || (cy && ab);  aLy = aLy || (cy && be);
            }
            {   // pair 1 (s = 2j+1)
                float fx = f.z, fy = f.w;
                float tolx = __fadd_rn(0.01f, __fmul_rn(1e-5f, __builtin_fabsf(fx)));
                float toly = __fadd_rn(0.01f, __fmul_rn(1e-5f, __builtin_fabsf(fy)));
                float mx = fminf(fminf(fminf(__builtin_fabsf(lxk[0] - fx),
                                             __builtin_fabsf(lxk[1] - fx)),
                                       fminf(__builtin_fabsf(lxk[2] - fx),
                                             __builtin_fabsf(lxk[3] - fx))),
                                 __builtin_fabsf(lxk[4] - fx));
                float my = fminf(fminf(fminf(__builtin_fabsf(lyk[0] - fy),
                                             __builtin_fabsf(lyk[1] - fy)),
                                       fminf(__builtin_fabsf(lyk[2] - fy),
                                             __builtin_fabsf(lyk[3] - fy))),
                                 __builtin_fabsf(lyk[4] - fy));
                bool cx = (mx <= tolx) && (fy <= lasty);
                bool cy = (my <= toly) && (fx <= lastx);
                float fsum = fx + fy;
                bool ab = fsum > psum, be = fsum < psum;
                float sgn = ab ? 1.0f : (be ? -1.0f : 0.0f);
                o.z = cx ? sgn : 0.0f;
                o.w = cy ? sgn : 0.0f;
                aUx = aUx || (cx && ab);  aLx = aLx || (cx && be);
                aUy = aUy || (cy && ab);  aLy = aLy || (cy && be);
            }
            __builtin_nontemporal_store(o, (floatx4*)(gmrow + (size_t)j * 4));
        }
    }

    bool anyUx = __any(aUx);
    bool anyLx = __any(aLx);
    bool anyUy = __any(aUy);
    bool anyLy = __any(aLy);
    if (lane == 0) {
        float cxv = anyUx ? -1.0f : (anyLx ? 1.0f : 0.0f);
        float cyv = anyUy ? -1.0f : (anyLy ? 1.0f : 0.0f);
        *(float2*)(gc + ((size_t)rem) * 2) = make_float2(cxv, cyv);
    }
}

extern "C" void kernel_launch(void* const* d_in, const int* in_sizes, int n_in,
                              void* d_out, int out_size, void* d_ws, size_t ws_size,
                              hipStream_t stream) {
    const float* filtration = (const float*)d_in[0];   // (2000,2)
    const float* bars_h0    = (const float*)d_in[1];   // (2500,5)
    const float* bars_h1    = (const float*)d_in[2];   // (2500,5)
    const float* sample_pts = (const float*)d_in[3];   // (2500,2)

    float* out = (float*)d_out;
    float* o_stack = out;                                 // 2*P*R
    float* gm0     = o_stack + (size_t)2 * P * R;         // R*P*2S
    float* gc0     = gm0 + (size_t)R * P * 2 * S;         // R*P*2
    float* gm1     = gc0 + (size_t)R * P * 2;             // R*P*2S
    float* gc1     = gm1 + (size_t)R * P * 2 * S;         // R*P*2

    grad_kernel<<<(2 * R * P) / 4, 256, 0, stream>>>(filtration, bars_h0, bars_h1, sample_pts,
                                                     o_stack, gm0, gc0, gm1, gc1);
}

// Round 13
// 84.881 us; speedup vs baseline: 1.1488x; 1.1488x over previous
//
#include <hip/hip_runtime.h>

#define S 2000
#define P 2500
#define R 5
#define HALF (S / 2)      // 1000 float4 elements per row
#define NIT 16            // ceil(HALF/64)

typedef float floatx4 __attribute__((ext_vector_type(4)));

// BEST variant (R10, 85.0 us): 4 waves/WG, one (h,r,p) job per wave,
// filtration staged in LDS (zero global loads in hot loop), plain
// write-allocate stores (NT measured -15%, R12), no barriers after staging.
__global__ __launch_bounds__(256) void grad_kernel(
    const float* __restrict__ filtration,   // (S,2) interleaved
    const float* __restrict__ bars0,        // (P,R)
    const float* __restrict__ bars1,        // (P,R)
    const float* __restrict__ sample_pts,   // (P,2)
    float* __restrict__ out,                // (2,P,R)
    float* __restrict__ gm0, float* __restrict__ gc0,
    float* __restrict__ gm1, float* __restrict__ gc1)
{
    __shared__ floatx4 sf[HALF];           // 16 KB

    int tid = threadIdx.x;
    const floatx4* filt4 = (const floatx4*)filtration;
#pragma unroll
    for (int i = 0; i < NIT / 4; ++i) {
        int idx = tid + 256 * i;
        if (idx < HALF) sf[idx] = filt4[idx];
    }

    int job = blockIdx.x * 4 + (tid >> 6);   // h*(R*P) + r*P + p
    int lane = tid & 63;
    int h = job / (R * P);
    int rem = job - h * (R * P);
    int r = rem / P;
    int p = rem - r * P;

    const float* bars = h ? bars1 : bars0;
    float* gm = h ? gm1 : gm0;
    float* gc = h ? gc1 : gc0;

    float bar = bars[p * R + r];
    float scale = bar + 0.01f;               // GRID_RES
    float ptx = sample_pts[2 * p];
    float pty = sample_pts[2 * p + 1];
    float psum = ptx + pty;

    float lxk[5], lyk[5];
#pragma unroll
    for (int k = 0; k < 5; ++k) {
        float ks = (float)(k - 2) * scale;   // exact mul, k-2 in {-2..2}
        lxk[k] = ks + ptx;                   // single rounding (matches np)
        lyk[k] = ks + pty;
    }
    float lastx = lxk[4];
    float lasty = lyk[4];

    if (lane == 0) out[(size_t)h * (P * R) + p * R + r] = bar;

    float* gmrow = gm + ((size_t)rem) * (size_t)(2 * S);

    bool aUx = false, aLx = false, aUy = false, aLy = false;

    __syncthreads();                         // staging done (only barrier)

#pragma unroll
    for (int it = 0; it < NIT; ++it) {
        int j = lane + 64 * it;
        if (it < NIT - 1 || j < HALF) {      // compile-time for it<15
            floatx4 f = sf[j];               // ds_read_b128 (lgkmcnt)
            floatx4 o;
            {   // pair 0 (s = 2j)
                float fx = f.x, fy = f.y;
                float tolx = __fadd_rn(0.01f, __fmul_rn(1e-5f, __builtin_fabsf(fx)));
                float toly = __fadd_rn(0.01f, __fmul_rn(1e-5f, __builtin_fabsf(fy)));
                // min(|d_k|) <= tol  <=>  any(|d_k| <= tol)  (exact)
                float mx = fminf(fminf(fminf(__builtin_fabsf(lxk[0] - fx),
                                             __builtin_fabsf(lxk[1] - fx)),
                                       fminf(__builtin_fabsf(lxk[2] - fx),
                                             __builtin_fabsf(lxk[3] - fx))),
                                 __builtin_fabsf(lxk[4] - fx));
                float my = fminf(fminf(fminf(__builtin_fabsf(lyk[0] - fy),
                                             __builtin_fabsf(lyk[1] - fy)),
                                       fminf(__builtin_fabsf(lyk[2] - fy),
                                             __builtin_fabsf(lyk[3] - fy))),
                                 __builtin_fabsf(lyk[4] - fy));
                bool cx = (mx <= tolx) && (fy <= lasty);
                bool cy = (my <= toly) && (fx <= lastx);
                float fsum = fx + fy;
                bool ab = fsum > psum, be = fsum < psum;
                float sgn = ab ? 1.0f : (be ? -1.0f : 0.0f);
                o.x = cx ? sgn : 0.0f;
                o.y = cy ? sgn : 0.0f;
                aUx = aUx || (cx && ab);  aLx = aLx || (cx && be);
                aUy = aUy || (cy && ab);  aLy = aLy || (cy && be);
            }
            {   // pair 1 (s = 2j+1)
                float fx = f.z, fy = f.w;
                float tolx = __fadd_rn(0.01f, __fmul_rn(1e-5f, __builtin_fabsf(fx)));
                float toly = __fadd_rn(0.01f, __fmul_rn(1e-5f, __builtin_fabsf(fy)));
                float mx = fminf(fminf(fminf(__builtin_fabsf(lxk[0] - fx),
                                             __builtin_fabsf(lxk[1] - fx)),
                                       fminf(__builtin_fabsf(lxk[2] - fx),
                                             __builtin_fabsf(lxk[3] - fx))),
                                 __builtin_fabsf(lxk[4] - fx));
                float my = fminf(fminf(fminf(__builtin_fabsf(lyk[0] - fy),
                                             __builtin_fabsf(lyk[1] - fy)),
                                       fminf(__builtin_fabsf(lyk[2] - fy),
                                             __builtin_fabsf(lyk[3] - fy))),
                                 __builtin_fabsf(lyk[4] - fy));
                bool cx = (mx <= tolx) && (fy <= lasty);
                bool cy = (my <= toly) && (fx <= lastx);
                float fsum = fx + fy;
                bool ab = fsum > psum, be = fsum < psum;
                float sgn = ab ? 1.0f : (be ? -1.0f : 0.0f);
                o.z = cx ? sgn : 0.0f;
                o.w = cy ? sgn : 0.0f;
                aUx = aUx || (cx && ab);  aLx = aLx || (cx && be);
                aUy = aUy || (cy && ab);  aLy = aLy || (cy && be);
            }
            *(floatx4*)(gmrow + (size_t)j * 4) = o;   // store: vmcnt free-runs
        }
    }

    bool anyUx = __any(aUx);
    bool anyLx = __any(aLx);
    bool anyUy = __any(aUy);
    bool anyLy = __any(aLy);
    if (lane == 0) {
        float cxv = anyUx ? -1.0f : (anyLx ? 1.0f : 0.0f);
        float cyv = anyUy ? -1.0f : (anyLy ? 1.0f : 0.0f);
        *(float2*)(gc + ((size_t)rem) * 2) = make_float2(cxv, cyv);
    }
}

extern "C" void kernel_launch(void* const* d_in, const int* in_sizes, int n_in,
                              void* d_out, int out_size, void* d_ws, size_t ws_size,
                              hipStream_t stream) {
    const float* filtration = (const float*)d_in[0];   // (2000,2)
    const float* bars_h0    = (const float*)d_in[1];   // (2500,5)
    const float* bars_h1    = (const float*)d_in[2];   // (2500,5)
    const float* sample_pts = (const float*)d_in[3];   // (2500,2)

    float* out = (float*)d_out;
    float* o_stack = out;                                 // 2*P*R
    float* gm0     = o_stack + (size_t)2 * P * R;         // R*P*2S
    float* gc0     = gm0 + (size_t)R * P * 2 * S;         // R*P*2
    float* gm1     = gc0 + (size_t)R * P * 2;             // R*P*2S
    float* gc1     = gm1 + (size_t)R * P * 2 * S;         // R*P*2

    grad_kernel<<<(2 * R * P) / 4, 256, 0, stream>>>(filtration, bars_h0, bars_h1, sample_pts,
                                                     o_stack, gm0, gc0, gm1, gc1);
}